// Round 1
// baseline (261.033 us; speedup 1.0000x reference)
//
#include <hip/hip_runtime.h>
#include <hip/hip_bf16.h>

// SAGAN attention: B=8, C=64, N=H*W=4096, Cr=8. gamma initialized to 0 in the
// reference, but we compute the full attention honestly and scale by gamma.
//
// ws layout (bytes):
//   [0      , 512K )  Qp : [b][n][8] bf16   (Wf.x * log2e, packed per query -> one B-frag)
//   [512K   , 1M   )  Kp : [b][n][8] bf16   (Wg.x, packed per key -> one A-frag row)
//   [1M     , 5M   )  VT : [b][c][n] bf16   (Wh.x)
//   [5M     , 5M+16)  zero block (A-frag zero padding for k>=8 lanes)

#define B_ 8
#define C_ 64
#define N_ 4096
#define LOG2E 1.4426950408889634f

typedef __attribute__((ext_vector_type(8))) __bf16 bf16x8;
typedef __attribute__((ext_vector_type(4))) float  f32x4;

union U16B { uint4 u; bf16x8 b; };

static __device__ inline uint pack_bf2(float a, float b) {
  __hip_bfloat162 h = __float22bfloat162_rn(make_float2(a, b));
  uint r; __builtin_memcpy(&r, &h, 4); return r;
}
static __device__ inline ushort f2bf(float a) {
  __hip_bfloat16 h = __float2bfloat16(a);
  ushort r; __builtin_memcpy(&r, &h, 2); return r;
}

// ---------------- projection: Q/K/V from x ----------------
__global__ __launch_bounds__(256) void proj_kernel(
    const float* __restrict__ x,  const float* __restrict__ Wf,
    const float* __restrict__ Wg, const float* __restrict__ Wh,
    ushort* __restrict__ Qp, ushort* __restrict__ Kp,
    ushort* __restrict__ VT, uint* __restrict__ zb)
{
  const int tid = blockIdx.x * 256 + threadIdx.x;   // 0..32767 = b*4096+n
  if (tid < 4) zb[tid] = 0u;                        // zero block (ws is poisoned)
  const int b = tid >> 12, n = tid & (N_ - 1);
  const float* xb = x + (size_t)b * C_ * N_ + n;

  float xr[64];
#pragma unroll
  for (int c = 0; c < 64; ++c) xr[c] = xb[(size_t)c * N_];

  float fa[8], ga[8];
#pragma unroll
  for (int d = 0; d < 8; ++d) {
    float aq = 0.f, ak = 0.f;
#pragma unroll
    for (int c = 0; c < 64; ++c) { aq += Wf[d*64+c] * xr[c]; ak += Wg[d*64+c] * xr[c]; }
    fa[d] = aq * LOG2E;   // fold log2(e): softmax uses exp2 directly
    ga[d] = ak;
  }
  uint4 qv, kv;
  qv.x = pack_bf2(fa[0], fa[1]); qv.y = pack_bf2(fa[2], fa[3]);
  qv.z = pack_bf2(fa[4], fa[5]); qv.w = pack_bf2(fa[6], fa[7]);
  kv.x = pack_bf2(ga[0], ga[1]); kv.y = pack_bf2(ga[2], ga[3]);
  kv.z = pack_bf2(ga[4], ga[5]); kv.w = pack_bf2(ga[6], ga[7]);
  *(uint4*)(Qp + (size_t)tid * 8) = qv;
  *(uint4*)(Kp + (size_t)tid * 8) = kv;

#pragma unroll 4
  for (int o = 0; o < 64; ++o) {
    float a = 0.f;
#pragma unroll
    for (int c = 0; c < 64; ++c) a += Wh[o*64+c] * xr[c];
    VT[((size_t)(b*64 + o)) * N_ + n] = f2bf(a);
  }
}

// ---------------- fused flash attention + epilogue ----------------
// grid (64, 8): blockIdx.x = q-tile (64 queries), blockIdx.y = b.
// 4 waves/block, 16 queries/wave. S^T = K*Q^T via mfma so each lane owns one
// query column -> no in-loop cross-lane softmax reductions.
__global__ __launch_bounds__(256) void attn_kernel(
    const ushort* __restrict__ Qp, const ushort* __restrict__ Kp,
    const ushort* __restrict__ VT, const uint* __restrict__ zb,
    const float* __restrict__ x,   const float* __restrict__ gamma,
    float* __restrict__ out)
{
  __shared__ __align__(16) float smemf[4160];   // 16640 B: V slab 8K | P 4x2K ; reused as O tile
  char* smem = (char*)smemf;

  const int b   = blockIdx.y;
  const int q0  = blockIdx.x * 64;
  const int tid = threadIdx.x;
  const int w   = tid >> 6;
  const int l   = tid & 63;
  const int l15 = l & 15, lq = l >> 4;

  // Q B-fragment, hoisted (n = q = l15; k>=8 garbage is multiplied by A zeros)
  U16B qf; qf.u = *(const uint4*)(Qp + ((size_t)b * N_ + q0 + w * 16 + l15) * 8);

  f32x4 O[4] = {{0,0,0,0},{0,0,0,0},{0,0,0,0},{0,0,0,0}};
  float L = 0.f;
  const uint4* zb16 = (const uint4*)zb;
  char* Pw = smem + 8192 + w * 2048;            // wave-private P region (A-frag linear)

  const int sc = tid >> 2;                      // staging: c row 0..63
  const int sj = (tid & 3) * 2;                 // staging: 16B-block pair base

  for (int jt = 0; jt < 64; ++jt) {
    const int j0 = jt * 64;
    __syncthreads();
    { // stage V slab [64c x 64j] bf16 -> LDS, 16B blocks rotated by c (bank spread)
      const ushort* src = VT + ((size_t)(b*64 + sc)) * N_ + j0 + sj * 8;
      uint4 v0 = *(const uint4*)src;
      uint4 v1 = *(const uint4*)(src + 8);
      uint4* vl = (uint4*)smem;
      vl[sc*8 + ((sj     + sc) & 7)] = v0;
      vl[sc*8 + ((sj + 1 + sc) & 7)] = v1;
    }
    __syncthreads();

    // S^T tiles: A = K (m=j, k=d zero-padded to 32), B = Q (n=q)
    f32x4 St[4];
#pragma unroll
    for (int t = 0; t < 4; ++t) {
      const uint4* ka = (l < 16)
          ? (const uint4*)(Kp + ((size_t)b * N_ + j0 + t*16 + l15) * 8)
          : zb16;
      U16B kf; kf.u = *ka;
      St[t] = __builtin_amdgcn_mfma_f32_16x16x32_bf16(kf.b, qf.b,
                (f32x4){0.f,0.f,0.f,0.f}, 0, 0, 0);
    }

    // p = exp2(s'), accumulate denominator, pack pairs, scatter into A-frag layout
#pragma unroll
    for (int t = 0; t < 4; ++t) {
      float p0 = exp2f(St[t][0]), p1 = exp2f(St[t][1]);
      float p2 = exp2f(St[t][2]), p3 = exp2f(St[t][3]);
      L += (p0 + p1) + (p2 + p3);
      uint2 pk; pk.x = pack_bf2(p0, p1); pk.y = pack_bf2(p2, p3);
      const int dst16 = (t>>1)*64 + ((t&1)*2 + (lq>>1))*16 + l15;
      *(uint2*)(Pw + dst16*16 + (lq&1)*8) = pk;
    }
    U16B pa0, pa1;
    pa0.u = *(const uint4*)(Pw + l * 16);
    pa1.u = *(const uint4*)(Pw + (64 + l) * 16);

    // O += P * V  (A = P, B = V: n=c, k=j)
    const uint4* vl = (const uint4*)smem;
#pragma unroll
    for (int t = 0; t < 4; ++t) {
      const int c = t*16 + l15;
      U16B vf0; vf0.u = vl[c*8 + ((lq     + c) & 7)];
      O[t] = __builtin_amdgcn_mfma_f32_16x16x32_bf16(pa0.b, vf0.b, O[t], 0, 0, 0);
      U16B vf1; vf1.u = vl[c*8 + ((4 + lq + c) & 7)];
      O[t] = __builtin_amdgcn_mfma_f32_16x16x32_bf16(pa1.b, vf1.b, O[t], 0, 0, 0);
    }
  }

  // softmax denominator: lane holds partial sum for q=l15; fold quads
  L += __shfl_xor(L, 16);
  L += __shfl_xor(L, 32);
  float Linv = 1.f / L;
  float li[4];
#pragma unroll
  for (int r = 0; r < 4; ++r) li[r] = __shfl(Linv, lq*4 + r);

  __syncthreads();                 // all PV reads done; reuse smem as O tile [64][65]
  float* Ot = smemf;
#pragma unroll
  for (int t = 0; t < 4; ++t)
#pragma unroll
    for (int r = 0; r < 4; ++r)
      Ot[(w*16 + lq*4 + r) * 65 + t*16 + l15] = O[t][r] * li[r];
  __syncthreads();

  // epilogue: out[b][c][q0+n] = gamma * O + x, coalesced
  const float g = gamma[0];
  const int n = tid & 63, ch = tid >> 6;
#pragma unroll
  for (int cc = 0; cc < 16; ++cc) {
    const int c = ch*16 + cc;
    const size_t oi = ((size_t)(b*64 + c)) * N_ + q0 + n;
    out[oi] = g * Ot[n*65 + c] + x[oi];
  }
}

extern "C" void kernel_launch(void* const* d_in, const int* in_sizes, int n_in,
                              void* d_out, int out_size, void* d_ws, size_t ws_size,
                              hipStream_t stream) {
  const float* x     = (const float*)d_in[0];
  const float* Wf    = (const float*)d_in[1];
  const float* Wg    = (const float*)d_in[2];
  const float* Wh    = (const float*)d_in[3];
  const float* gamma = (const float*)d_in[4];
  float* out = (float*)d_out;
  char* ws = (char*)d_ws;
  ushort* Qp = (ushort*)(ws);
  ushort* Kp = (ushort*)(ws + 512 * 1024);
  ushort* VT = (ushort*)(ws + 1024 * 1024);
  uint*   zb = (uint*)  (ws + 5 * 1024 * 1024);

  proj_kernel<<<128, 256, 0, stream>>>(x, Wf, Wg, Wh, Qp, Kp, VT, zb);
  attn_kernel<<<dim3(64, 8), 256, 0, stream>>>(Qp, Kp, VT, zb, x, gamma, out);
}

// Round 2
// 128.310 us; speedup vs baseline: 2.0344x; 2.0344x over previous
//
#include <hip/hip_runtime.h>
#include <hip/hip_bf16.h>

// SAGAN attention B=8, C=64, N=4096, Cr=8.
// Pipeline: transpose(x->xT bf16) -> proj GEMM (Q,K,V) -> flash attn (j-split x2,
// 32x32x16 PV MFMA, 3-buffer LDS pipeline, 1 barrier/tile) -> combine epilogue.
//
// ws layout (bytes):
//   [0    , 0.5M)  Qp [b][n][8]  bf16 (Wf.x * log2e)
//   [0.5M , 1M  )  Kp [b][n][8]  bf16
//   [1M   , 5M  )  VT [b][c][n]  bf16
//   [5M   , 5M+64) zero block (MFMA zero padding)
//   [6M   , 22M )  Opart [jh][b][n][c] fp32  (xT [b][n][c] bf16 overlaps 6M..10M, dead by attn)
//   [22M  , 22.25M) Lpart [jh][b][n] fp32

#define N_ 4096
#define LOG2E 1.4426950408889634f

typedef __attribute__((ext_vector_type(8)))  __bf16 bf16x8;
typedef __attribute__((ext_vector_type(4)))  float  f32x4;
typedef __attribute__((ext_vector_type(16))) float  f32x16;

union U16B { uint4 u; bf16x8 b; };

static __device__ inline uint pack_bf2(float a, float b) {
  __hip_bfloat162 h = __float22bfloat162_rn(make_float2(a, b));
  uint r; __builtin_memcpy(&r, &h, 4); return r;
}
static __device__ inline ushort f2bf(float a) {
  __hip_bfloat16 h = __float2bfloat16(a);
  ushort r; __builtin_memcpy(&r, &h, 2); return r;
}

// ---------------- pass 1: x [b][c][n] fp32 -> xT [b][n][c] bf16 ----------------
__global__ __launch_bounds__(256) void transpose_kernel(
    const float* __restrict__ x, ushort* __restrict__ xT, uint* __restrict__ zb)
{
  __shared__ float T[64 * 65];
  const int b = blockIdx.y, n0 = blockIdx.x * 64, tid = threadIdx.x;
  if (blockIdx.x == 0 && blockIdx.y == 0 && tid < 16) zb[tid] = 0u;
  const int nl = tid & 63, cw = tid >> 6;
#pragma unroll
  for (int i = 0; i < 16; ++i) {
    const int c = i * 4 + cw;
    T[c * 65 + nl] = x[((size_t)(b * 64 + c)) * N_ + n0 + nl];
  }
  __syncthreads();
  const int n = tid >> 2, cq = (tid & 3) * 16;
  uint o[8];
#pragma unroll
  for (int j = 0; j < 8; ++j)
    o[j] = pack_bf2(T[(cq + 2 * j) * 65 + n], T[(cq + 2 * j + 1) * 65 + n]);
  ushort* dst = xT + ((size_t)(b * N_ + n0 + n)) * 64 + cq;
  *(uint4*)dst       = make_uint4(o[0], o[1], o[2], o[3]);
  *(uint4*)(dst + 8) = make_uint4(o[4], o[5], o[6], o[7]);
}

// ---------------- pass 2: projection GEMM via MFMA ----------------
// W rows 0-7 = Wf*log2e, 8-15 = Wg, 16-79 = Wh.  A = W (bf16, LDS), B = xT rows.
__global__ __launch_bounds__(256) void proj_kernel(
    const ushort* __restrict__ xT, const float* __restrict__ Wf,
    const float* __restrict__ Wg,  const float* __restrict__ Wh,
    ushort* __restrict__ Qp, ushort* __restrict__ Kp, ushort* __restrict__ VT)
{
  __shared__ __align__(16) ushort Wb[80 * 72];   // row stride 144 B (pad: 2-way banks)
  const int b = blockIdx.y, nb = blockIdx.x * 64, tid = threadIdx.x;
#pragma unroll
  for (int i = 0; i < 20; ++i) {
    const int e = i * 256 + tid;
    const int row = e >> 6, col = e & 63;
    float v;
    if (row < 8)       v = Wf[row * 64 + col] * LOG2E;
    else if (row < 16) v = Wg[(row - 8) * 64 + col];
    else               v = Wh[(row - 16) * 64 + col];
    Wb[row * 72 + col] = f2bf(v);
  }
  __syncthreads();
  const int l = tid & 63, w = tid >> 6;
  const int l15 = l & 15, lq = l >> 4;
  const int n = nb + w * 16 + l15;
  const ushort* xb = xT + ((size_t)(b * N_ + n)) * 64 + lq * 8;
  U16B bf0, bf1;
  bf0.u = *(const uint4*)xb;
  bf1.u = *(const uint4*)(xb + 32);
  f32x4 acc[5];
#pragma unroll
  for (int mt = 0; mt < 5; ++mt) {
    U16B a0, a1;
    a0.u = *(const uint4*)(Wb + (mt * 16 + l15) * 72 + lq * 8);
    a1.u = *(const uint4*)(Wb + (mt * 16 + l15) * 72 + 32 + lq * 8);
    f32x4 c0 = __builtin_amdgcn_mfma_f32_16x16x32_bf16(a0.b, bf0.b, (f32x4){0.f,0.f,0.f,0.f}, 0, 0, 0);
    acc[mt]  = __builtin_amdgcn_mfma_f32_16x16x32_bf16(a1.b, bf1.b, c0, 0, 0, 0);
  }
  { // m-tile 0: rows 0-7 -> Q, 8-15 -> K   (C row = lq*4+r, col = n = l15)
    uint lo = pack_bf2(acc[0][0], acc[0][1]);
    uint hi = pack_bf2(acc[0][2], acc[0][3]);
    ushort* dst = (lq < 2 ? Qp : Kp) + ((size_t)(b * N_ + n)) * 8 + (lq & 1) * 4;
    *(uint2*)dst = make_uint2(lo, hi);
  }
#pragma unroll
  for (int mt = 1; mt < 5; ++mt)
#pragma unroll
    for (int r = 0; r < 4; ++r) {
      const int c = (mt - 1) * 16 + lq * 4 + r;
      VT[((size_t)(b * 64 + c)) * N_ + n] = f2bf(acc[mt][r]);
    }
}

// ---------------- pass 3: flash attention, j-split x2 ----------------
// grid (32 qtile, 2 jh, 8 b), 256 thr. Wave = 32 q. 32 j-tiles of 64 per block.
// LDS: V 3 x (64 rows x 144B) = 27648 | P 4 waves x (32 rows x 144B) = 18432.
__global__ __launch_bounds__(256) void attn_kernel(
    const ushort* __restrict__ Qp, const ushort* __restrict__ Kp,
    const ushort* __restrict__ VT, const uint* __restrict__ zb,
    float* __restrict__ Opart, float* __restrict__ Lpart)
{
  __shared__ __align__(16) char smem[46080];
  const int b = blockIdx.z, jh = blockIdx.y;
  const int q0 = blockIdx.x * 128;
  const int tid = threadIdx.x, w = tid >> 6, l = tid & 63;
  const int l15 = l & 15, lq = l >> 4, l31 = l & 31, lq1 = l >> 5;
  const int qw = q0 + w * 32;
  char* Pw = smem + 27648 + w * 4608;
  const uint4* zb16 = (const uint4*)zb;

  U16B qf0, qf1;
  qf0.u = *(const uint4*)(Qp + ((size_t)(b * N_ + qw + l15)) * 8);
  qf1.u = *(const uint4*)(Qp + ((size_t)(b * N_ + qw + 16 + l15)) * 8);

  const int jbase = jh * 2048;
  const int sc = tid >> 2, sj = (tid & 3) * 2;
  const ushort* Vsrc = VT + ((size_t)(b * 64 + sc)) * N_ + jbase + sj * 8;
  const int ws0 = sc * 144 + (((sj)     ^ (sc >> 3)) & 7) * 16;
  const int ws1 = sc * 144 + (((sj + 1) ^ (sc >> 3)) & 7) * 16;

  // preload K frags + V slab for jt = 0
  U16B kf[4], kfn[4];
#pragma unroll
  for (int t = 0; t < 4; ++t) {
    const uint4* ka = (l < 16)
        ? (const uint4*)(Kp + ((size_t)(b * N_ + jbase + t * 16 + l15)) * 8) : zb16;
    kf[t].u = *ka;
  }
  uint4 v0 = *(const uint4*)Vsrc;
  uint4 v1 = *(const uint4*)(Vsrc + 8);
  *(uint4*)(smem + ws0) = v0;
  *(uint4*)(smem + ws1) = v1;
  __syncthreads();

  f32x16 O0 = {0,0,0,0,0,0,0,0,0,0,0,0,0,0,0,0};
  f32x16 O1 = {0,0,0,0,0,0,0,0,0,0,0,0,0,0,0,0};
  float L0 = 0.f, L1 = 0.f;

  int cur = 0;
  for (int jt = 0; jt < 32; ++jt) {
    const int nxt = (cur == 2) ? 0 : cur + 1;
    if (jt < 31) {  // prefetch next K frags + V slab into regs (latency spans body)
      const int jn = jbase + (jt + 1) * 64;
#pragma unroll
      for (int t = 0; t < 4; ++t) {
        const uint4* ka = (l < 16)
            ? (const uint4*)(Kp + ((size_t)(b * N_ + jn + t * 16 + l15)) * 8) : zb16;
        kfn[t].u = *ka;
      }
      v0 = *(const uint4*)(Vsrc + (jt + 1) * 64);
      v1 = *(const uint4*)(Vsrc + (jt + 1) * 64 + 8);
    }
    // S^T = K * Q^T : A = K (m=j, d zero-padded), B = Q (n=q)
    f32x4 St0[4], St1[4];
#pragma unroll
    for (int t = 0; t < 4; ++t) {
      St0[t] = __builtin_amdgcn_mfma_f32_16x16x32_bf16(kf[t].b, qf0.b, (f32x4){0.f,0.f,0.f,0.f}, 0, 0, 0);
      St1[t] = __builtin_amdgcn_mfma_f32_16x16x32_bf16(kf[t].b, qf1.b, (f32x4){0.f,0.f,0.f,0.f}, 0, 0, 0);
    }
    // softmax numerators -> P (wave-private LDS, A-layout rows, xor-swizzled slots)
#pragma unroll
    for (int u = 0; u < 2; ++u) {
      const int prow = u * 16 + l15;
      const int rot = prow >> 3;
      char* base = Pw + prow * 144 + (lq & 1) * 8;
#pragma unroll
      for (int t = 0; t < 4; ++t) {
        const f32x4 s = u ? St1[t] : St0[t];
        const float p0 = __builtin_amdgcn_exp2f(s[0]);
        const float p1 = __builtin_amdgcn_exp2f(s[1]);
        const float p2 = __builtin_amdgcn_exp2f(s[2]);
        const float p3 = __builtin_amdgcn_exp2f(s[3]);
        const float ps = (p0 + p1) + (p2 + p3);
        if (u) L1 += ps; else L0 += ps;
        const int slot = ((t * 2 + (lq >> 1)) ^ rot) & 7;
        *(uint2*)(base + slot * 16) = make_uint2(pack_bf2(p0, p1), pack_bf2(p2, p3));
      }
    }
    // O += P * V : A = P (m=q 32), B = V (n=c 32), k = j 16
    const char* Vb = smem + cur * 9216;
#pragma unroll
    for (int ks = 0; ks < 4; ++ks) {
      U16B pa;
      pa.u = *(const uint4*)(Pw + l31 * 144 + (((ks * 2 + lq1) ^ (l31 >> 3)) & 7) * 16);
      {
        const int c = l31;
        U16B vb; vb.u = *(const uint4*)(Vb + c * 144 + (((ks * 2 + lq1) ^ (c >> 3)) & 7) * 16);
        O0 = __builtin_amdgcn_mfma_f32_32x32x16_bf16(pa.b, vb.b, O0, 0, 0, 0);
      }
      {
        const int c = 32 + l31;
        U16B vb; vb.u = *(const uint4*)(Vb + c * 144 + (((ks * 2 + lq1) ^ (c >> 3)) & 7) * 16);
        O1 = __builtin_amdgcn_mfma_f32_32x32x16_bf16(pa.b, vb.b, O1, 0, 0, 0);
      }
    }
    if (jt < 31) {  // stage prefetched slab into next buffer
      char* Vn = smem + nxt * 9216;
      *(uint4*)(Vn + ws0) = v0;
      *(uint4*)(Vn + ws1) = v1;
#pragma unroll
      for (int t = 0; t < 4; ++t) kf[t] = kfn[t];
    }
    __syncthreads();
    cur = nxt;
  }

  // partial softmax denominators (per q, reduce over lq groups)
  L0 += __shfl_xor(L0, 16); L0 += __shfl_xor(L0, 32);
  L1 += __shfl_xor(L1, 16); L1 += __shfl_xor(L1, 32);
  float* Lp = Lpart + ((size_t)(jh * 8 + b)) * N_;
  if (lq == 0) Lp[qw + l15] = L0;
  if (lq == 1) Lp[qw + 16 + l15] = L1;

  // partial O: C rows q' = (reg&3) + 8*(reg>>2) + 4*lq1, col c = l31 (+32)
  float* Ob = Opart + (((size_t)(jh * 8 + b)) * N_ + qw) * 64;
#pragma unroll
  for (int g = 0; g < 4; ++g)
#pragma unroll
    for (int rr = 0; rr < 4; ++rr) {
      const int qp = rr + 8 * g + 4 * lq1;
      Ob[qp * 64 + l31]      = O0[g * 4 + rr];
      Ob[qp * 64 + 32 + l31] = O1[g * 4 + rr];
    }
}

// ---------------- pass 4: combine halves + normalize + gamma*o + x ----------------
__global__ __launch_bounds__(256) void combine_kernel(
    const float* __restrict__ Opart, const float* __restrict__ Lpart,
    const float* __restrict__ x, const float* __restrict__ gamma,
    float* __restrict__ out)
{
  __shared__ float T[64 * 65];
  const int b = blockIdx.y, n0 = blockIdx.x * 64, tid = threadIdx.x;
  const float g = gamma[0];
  const float* O0 = Opart + ((size_t)(b) * N_ + n0) * 64;
  const float* O1 = Opart + ((size_t)(8 + b) * N_ + n0) * 64;
#pragma unroll
  for (int i = 0; i < 16; ++i) {
    const int idx = i * 256 + tid;            // idx = n*64 + c
    const int n = idx >> 6, c = idx & 63;
    T[n * 65 + c] = O0[idx] + O1[idx];
  }
  __syncthreads();
  const int n = tid & 63, cq = (tid >> 6) * 16;
  const float l0 = Lpart[(size_t)(b) * N_ + n0 + n];
  const float l1 = Lpart[(size_t)(8 + b) * N_ + n0 + n];
  const float gr = g / (l0 + l1);
#pragma unroll
  for (int i = 0; i < 16; ++i) {
    const int c = cq + i;
    const size_t oi = ((size_t)(b * 64 + c)) * N_ + n0 + n;
    out[oi] = gr * T[n * 65 + c] + x[oi];
  }
}

extern "C" void kernel_launch(void* const* d_in, const int* in_sizes, int n_in,
                              void* d_out, int out_size, void* d_ws, size_t ws_size,
                              hipStream_t stream) {
  const float* x     = (const float*)d_in[0];
  const float* Wf    = (const float*)d_in[1];
  const float* Wg    = (const float*)d_in[2];
  const float* Wh    = (const float*)d_in[3];
  const float* gamma = (const float*)d_in[4];
  float* out = (float*)d_out;
  char* ws = (char*)d_ws;

  ushort* Qp    = (ushort*)(ws);
  ushort* Kp    = (ushort*)(ws + 512 * 1024);
  ushort* VT    = (ushort*)(ws + 1024 * 1024);
  uint*   zb    = (uint*)  (ws + 5 * 1024 * 1024);
  float*  Opart = (float*) (ws + 6 * 1024 * 1024);   // 16 MB
  float*  Lpart = (float*) (ws + 22 * 1024 * 1024);  // 256 KB
  ushort* xT    = (ushort*)(ws + 6 * 1024 * 1024);   // 4 MB, overlaps Opart (dead by attn)

  transpose_kernel<<<dim3(64, 8), 256, 0, stream>>>(x, xT, zb);
  proj_kernel     <<<dim3(64, 8), 256, 0, stream>>>(xT, Wf, Wg, Wh, Qp, Kp, VT);
  attn_kernel     <<<dim3(32, 2, 8), 256, 0, stream>>>(Qp, Kp, VT, zb, Opart, Lpart);
  combine_kernel  <<<dim3(64, 8), 256, 0, stream>>>(Opart, Lpart, x, gamma, out);
}